// Round 6
// baseline (7353.166 us; speedup 1.0000x reference)
//
#include <hip/hip_runtime.h>
#include <cstdint>
#include <cstddef>

typedef unsigned short u16;

#define F_DIM   128
#define HF_DIM  512
#define NRBF    20
#define NOUT    384

__device__ __forceinline__ float bf2f(u16 u){
    union { unsigned int i; float f; } v; v.i = ((unsigned int)u) << 16; return v.f;
}
__device__ __forceinline__ u16 f2bf(float f){
    union { float f; unsigned int i; } v; v.f = f;
    unsigned int x = v.i;
    unsigned int r = x + 0x7fffu + ((x >> 16) & 1u);   // RTNE
    return (u16)(r >> 16);
}
__device__ __forceinline__ float silu(float x){
    return x * __fdividef(1.0f, 1.0f + __expf(-x));
}

// ---------------------------------------------------------------------------
// S1: LayerNorm, literal. One block (128 threads) per node. f32 out.
// ---------------------------------------------------------------------------
__global__ __launch_bounds__(128) void s1_ln(
    const float* __restrict__ s_j, const float* __restrict__ ln_g,
    const float* __restrict__ ln_b, float* __restrict__ inp, int N)
{
    __shared__ float ps[2], pss[2];
    const int n = blockIdx.x;
    const int f = threadIdx.x;
    float x = s_j[(size_t)n * F_DIM + f];
    float s = x, ss = x * x;
    #pragma unroll
    for (int o = 1; o < 64; o <<= 1){
        s  += __shfl_xor(s,  o);
        ss += __shfl_xor(ss, o);
    }
    const int wid = f >> 6;
    if ((f & 63) == 0){ ps[wid] = s; pss[wid] = ss; }
    __syncthreads();
    const float S  = ps[0] + ps[1];
    const float SS = pss[0] + pss[1];
    const float mu  = S * (1.f / 128.f);
    const float var = SS * (1.f / 128.f) - mu * mu;
    const float r   = rsqrtf(var + 1e-5f);
    inp[(size_t)n * F_DIM + f] = (x - mu) * r * ln_g[f] + ln_b[f];
}

// ---------------------------------------------------------------------------
// S2: QKV projection, scalar. One block (512 threads) per node; thread = col.
// q/k/v stored bf16 (intermediate precision ok for 2% budget).
// ---------------------------------------------------------------------------
__global__ __launch_bounds__(512) void s2_qkv(
    const float* __restrict__ inp,
    const float* __restrict__ Wq, const float* __restrict__ bq,
    const float* __restrict__ Wk, const float* __restrict__ bk,
    const float* __restrict__ Wv, const float* __restrict__ bv,
    u16* __restrict__ qo, u16* __restrict__ ko, u16* __restrict__ vo, int N)
{
    __shared__ float a[F_DIM];
    const int n = blockIdx.x;
    const int col = threadIdx.x;
    if (col < F_DIM) a[col] = inp[(size_t)n * F_DIM + col];
    __syncthreads();
    float aq = bq[col], ak = bk[col], av = bv[col];
    for (int k = 0; k < F_DIM; k++){
        const float x = a[k];
        aq += x * Wq[k * HF_DIM + col];
        ak += x * Wk[k * HF_DIM + col];
        av += x * Wv[k * HF_DIM + col];
    }
    qo[(size_t)n * HF_DIM + col] = f2bf(aq);
    ko[(size_t)n * HF_DIM + col] = f2bf(ak);
    vo[(size_t)n * HF_DIM + col] = f2bf(av);
}

// ---------------------------------------------------------------------------
// S3: fused edge pipeline + dense, scalar. Block = 32 edges, 256 threads.
// Phase A: thread = (edge, head, half): rbf matvecs, attn, msg -> LDS (bf16).
// Phase B: 48 (edge,col) outputs per thread, 512-step scalar dot, f32 out.
// ---------------------------------------------------------------------------
__global__ __launch_bounds__(256) void s3_edge_dense(
    const float* __restrict__ dist, const int* __restrict__ nbrs,
    const u16* __restrict__ q_ws, const u16* __restrict__ k_ws, const u16* __restrict__ v_ws,
    const float* __restrict__ dkW, const float* __restrict__ dkb,
    const float* __restrict__ dvW, const float* __restrict__ dvb,
    const float* __restrict__ dW, const float* __restrict__ db,
    float* __restrict__ out, int E, int N)
{
    __shared__ __align__(16) u16 msg_s[32][520];
    __shared__ float rbf_sh[32][21];
    __shared__ float env_sh[32];
    const int tid = threadIdx.x;
    const int e0 = blockIdx.x * 32;

    if (tid < 32){
        int de = e0 + tid; if (de >= E) de = E - 1;
        float d = dist[de];
        env_sh[tid] = 0.5f * (__cosf(0.62831853071f * d) + 1.0f);   // pi/5
        const float delta = 5.0f / 19.0f;   // CUTOFF/(N_RBF-1)
        const float invd  = 19.0f / 5.0f;
        #pragma unroll
        for (int r = 0; r < NRBF; r++){
            float t = (d - delta * (float)r) * invd;
            rbf_sh[tid][r] = __expf(-0.5f * t * t);
        }
    }
    __syncthreads();

    // ---- Phase A: build msg tile in LDS (bf16) ----
    {
        const int e_l = tid >> 3, sub = tid & 7;
        const int h = sub >> 1, half = sub & 1;
        const int fb = h * F_DIM + half * 64;          // this thread's 64 feats
        int e = e0 + e_l; if (e >= E) e = E - 1;
        int i_idx = nbrs[2*e + 0];
        int j_idx = nbrs[2*e + 1];
        i_idx = (i_idx < 0) ? 0 : (i_idx >= N ? N-1 : i_idx);
        j_idx = (j_idx < 0) ? 0 : (j_idx >= N ? N-1 : j_idx);
        float rbf[NRBF];
        #pragma unroll
        for (int r = 0; r < NRBF; r++) rbf[r] = rbf_sh[e_l][r];
        const float env = env_sh[e_l];
        const u16* qrow = q_ws + (size_t)i_idx * HF_DIM + fb;
        const u16* krow = k_ws + (size_t)j_idx * HF_DIM + fb;
        const u16* vrow = v_ws + (size_t)j_idx * HF_DIM + fb;

        float attn = 0.f;
        for (int c = 0; c < 8; c++){
            const int f0 = c * 8;
            float a8[8];
            #pragma unroll
            for (int j = 0; j < 8; j++) a8[j] = dkb[fb + f0 + j];
            #pragma unroll
            for (int r = 0; r < NRBF; r++){
                const float rv = rbf[r];
                const float* wp = dkW + (size_t)r * HF_DIM + fb + f0;
                #pragma unroll
                for (int j = 0; j < 8; j++) a8[j] += rv * wp[j];
            }
            uint4 qu = *(const uint4*)(qrow + f0);
            uint4 ku = *(const uint4*)(krow + f0);
            const u16* qp = (const u16*)&qu;
            const u16* kp = (const u16*)&ku;
            #pragma unroll
            for (int j = 0; j < 8; j++)
                attn += bf2f(qp[j]) * silu(a8[j]) * bf2f(kp[j]);
        }
        attn += __shfl_xor(attn, 1);                   // combine the two halves
        const float scale = silu(attn) * env;

        for (int c = 0; c < 8; c++){
            const int f0 = c * 8;
            float a8[8];
            #pragma unroll
            for (int j = 0; j < 8; j++) a8[j] = dvb[fb + f0 + j];
            #pragma unroll
            for (int r = 0; r < NRBF; r++){
                const float rv = rbf[r];
                const float* wp = dvW + (size_t)r * HF_DIM + fb + f0;
                #pragma unroll
                for (int j = 0; j < 8; j++) a8[j] += rv * wp[j];
            }
            uint4 vu = *(const uint4*)(vrow + f0);
            const u16* vp = (const u16*)&vu;
            u16 ov[8];
            #pragma unroll
            for (int j = 0; j < 8; j++)
                ov[j] = f2bf(scale * bf2f(vp[j]) * silu(a8[j]));
            *(uint4*)&msg_s[e_l][fb + f0] = *(const uint4*)ov;
        }
    }
    __syncthreads();

    // ---- Phase B: scalar dense, f32 output ----
    for (int p = 0; p < 48; p++){
        const int idx = tid + p * 256;                 // 0 .. 12287
        const int e_l = idx / NOUT;
        const int col = idx - e_l * NOUT;
        const int grow = e0 + e_l;
        float acc = db[col];
        for (int k = 0; k < HF_DIM; k++)
            acc += bf2f(msg_s[e_l][k]) * dW[(size_t)k * NOUT + col];
        if (grow < E)
            out[(size_t)grow * NOUT + col] = acc;      // f32 write — THE fix
    }
}

// ---------------------------------------------------------------------------
extern "C" void kernel_launch(void* const* d_in, const int* in_sizes, int n_in,
                              void* d_out, int out_size, void* d_ws, size_t ws_size,
                              hipStream_t stream)
{
    const float* s_j  = (const float*)d_in[0];
    const float* dist = (const float*)d_in[1];
    const int*   nbrs = (const int*)d_in[2];
    const float* ln_g = (const float*)d_in[3];
    const float* ln_b = (const float*)d_in[4];
    const float* Wq   = (const float*)d_in[5];
    const float* bq   = (const float*)d_in[6];
    const float* Wk   = (const float*)d_in[7];
    const float* bk   = (const float*)d_in[8];
    const float* Wv   = (const float*)d_in[9];
    const float* bv   = (const float*)d_in[10];
    const float* dkW  = (const float*)d_in[11];
    const float* dkb  = (const float*)d_in[12];
    const float* dvW  = (const float*)d_in[13];
    const float* dvb  = (const float*)d_in[14];
    const float* dW   = (const float*)d_in[15];
    const float* db   = (const float*)d_in[16];
    const int N = in_sizes[0] / F_DIM;
    const int E = in_sizes[1];
    (void)n_in; (void)out_size; (void)ws_size;

    char* ws = (char*)d_ws;
    size_t off = 0;
    auto walloc = [&](size_t bytes) -> void* {
        void* p = ws + off;
        off += (bytes + 255) & ~(size_t)255;
        return p;
    };
    float* inp_ws = (float*)walloc((size_t)N * F_DIM * 4);
    u16*   q_ws   = (u16*)walloc((size_t)N * HF_DIM * 2);
    u16*   k_ws   = (u16*)walloc((size_t)N * HF_DIM * 2);
    u16*   v_ws   = (u16*)walloc((size_t)N * HF_DIM * 2);

    s1_ln<<<N, 128, 0, stream>>>(s_j, ln_g, ln_b, inp_ws, N);
    s2_qkv<<<N, 512, 0, stream>>>(inp_ws, Wq, bq, Wk, bk, Wv, bv,
                                  q_ws, k_ws, v_ws, N);
    s3_edge_dense<<<(E + 31)/32, 256, 0, stream>>>(
        dist, nbrs, q_ws, k_ws, v_ws,
        dkW, dkb, dvW, dvb, dW, db, (float*)d_out, E, N);
}